// Round 1
// 190.039 us; speedup vs baseline: 1.0133x; 1.0133x over previous
//
#include <hip/hip_runtime.h>
#include <stdint.h>

typedef uint32_t u32;
typedef uint64_t u64;

// BinaryNet on MI355X: everything after binarize() is {-1,0,+1}.
// Layer1 (9 taps, odd) -> exact +-1 per output -> 1 bit.
// Layer2 (36 taps, even) -> ternary -> (value bit, nonzero bit).
// All convs/FCs computed as XOR + popcount on packed sign bits.
//
// R6 structural change: phase-decorrelated launch. Old shape (512 blocks x 256
// threads) phase-locks 4 waves/block via __syncthreads and gives only 2
// blocks/CU -> all 8 waves/CU burst loads together, then ALL sit in the
// VALU-only eval with HBM idle. New shape: one wave per block, <<<B/64, 64>>>
// = 2048 blocks = 8 independent blocks/CU. Same waves/SIMD, same proven
// 45-deep load batches, byte-identical eval; but blocks drift out of phase so
// one wave's eval overlaps another's load burst -> HBM streams continuously.
// Coverage is bijective by construction: out[blockIdx.x*64 + lane].
// (R2/R5's ~2^32 absmax was poison in unwritten outputs -- a coverage bug in
// those rewrites, not a launch-shape HW constraint.)
//
// ws layout (u32 index) — footprint 324 bytes (ws[0..80]).
//   [0..3]   w1p[c]    : 9-bit, bit 3*ky+kx
//   [8..23]  w2q[d]    : u64, 36-bit, bit 12*ky+4*kx+c
//   [24..55] w3lo[e]   : u64, bits 0..63 of 72-bit, bit 8*(3*ky+kx)+d
//   [56..71] w3hi[e]   : u32, bits 64..71
//   [72..79] wf1[j]    : 16-bit, bit e
//   [80]     wf2       : 8-bit, bit j

// ---------------- weight prep (R3/R4-passing logic, unchanged) ----------------
__global__ void prep_weights(const float* __restrict__ w1, const float* __restrict__ w2,
                             const float* __restrict__ w3, const float* __restrict__ wfc1,
                             const float* __restrict__ wfc2, u32* __restrict__ ws) {
  const int tid = threadIdx.x;
  if (tid < 81) ws[tid] = 0;
  __syncthreads();
  for (int i = tid; i < 1612; i += 1024) {
    if (i < 36) {                       // w1 [4][9]
      const int c = i / 9, k = i % 9;
      if (w1[i] < 0.f) atomicOr(&ws[c], 1u << k);
    } else if (i < 324) {               // w2 [8][4][3][3]
      const int j = i - 36, d = j / 36, r = j % 36;
      const int c = r / 9, t = r % 9, ky = t / 3, kx = t % 3;
      const int bp = 12 * ky + 4 * kx + c;
      if (w2[j] < 0.f) atomicOr(&ws[8 + 2 * d + (bp >> 5)], 1u << (bp & 31));
    } else if (i < 1476) {              // w3 [16][8][3][3]
      const int j = i - 324, e = j / 72, r = j % 72;
      const int d = r / 9, t = r % 9, ky = t / 3, kx = t % 3;
      const int bp = 8 * (3 * ky + kx) + d;
      if (w3[j] < 0.f) {
        if (bp < 64) atomicOr(&ws[24 + 2 * e + (bp >> 5)], 1u << (bp & 31));
        else         atomicOr(&ws[56 + e], 1u << (bp - 64));
      }
    } else if (i < 1604) {              // wfc1 [8][16]
      const int j = i - 1476, row = j / 16, e = j % 16;
      if (wfc1[j] < 0.f) atomicOr(&ws[72 + row], 1u << e);
    } else {                            // wfc2 [1][8]
      const int j = i - 1604;
      if (wfc2[j] < 0.f) atomicOr(&ws[80], 1u << j);
    }
  }
}

// ---------------- fused kernel: 1 wave/block, deep-batch ballot staging ----------------
__global__ __launch_bounds__(64) void binnet(const float* __restrict__ x,
                                             const u32* __restrict__ ws,
                                             float* __restrict__ out) {
  __shared__ u64 st[228];
  const int lane = threadIdx.x;       // one wave per block
  const int b0 = blockIdx.x * 64;     // this block's 64 samples

  // Stage this wave's 64 samples' 225 sign words (flat float order):
  // word t = ballot over lanes of float [b0*225 + 64t + lane].
  // 5 groups of 45: all 45 coalesced loads issue before the ballot/store
  // drain (45 live floats ~ 55 VGPRs, fits the compiler's 64-VGPR target).
  const float* xw = x + (size_t)b0 * 225 + lane;
  if (lane < 3) st[225 + lane] = 0;   // zero tail words
  #pragma unroll
  for (int g = 0; g < 5; ++g) {
    float v[45];
    #pragma unroll
    for (int k = 0; k < 45; ++k) v[k] = xw[(g * 45 + k) * 64];
    #pragma unroll
    for (int k = 0; k < 45; ++k) {
      const u64 m = __ballot(v[k] < 0.f);
      if (lane == 0) st[g * 45 + k] = m;
    }
  }
  __syncthreads();  // single-wave barrier: near-free, orders LDS writes->reads

  // ---- Eval: byte-identical to the R3/R4-passing kernel ----
  const u64* stw = st;
  const int f0 = 225 * lane;
  const int w0 = f0 >> 6;
  const int sh = f0 & 63;
  u64 Wd[5];
  #pragma unroll
  for (int i = 0; i < 5; ++i) Wd[i] = stw[w0 + i];
  u64 Bv[4];
  #pragma unroll
  for (int i = 0; i < 4; ++i)
    Bv[i] = (Wd[i] >> sh) | ((Wd[i + 1] << (63 - sh)) << 1);  // sh==0 -> 0 contribution

  // rows: rb[r] bit k = sign(x[b,0,r,k])
  u32 rb[15];
  #pragma unroll
  for (int r = 0; r < 15; ++r) {
    const int f = 15 * r, w = f >> 6, o = f & 63;
    u64 v = Bv[w] >> o;
    if (o > 49) v |= Bv[w + 1] << (64 - o);
    rb[r] = (u32)v & 0x7FFFu;
  }

  // ---- Layer 1: 4ch, 15x15 -> 7x7, 9 taps (always +-1 out) ----
  const u32 w1p0 = ws[0], w1p1 = ws[1], w1p2 = ws[2], w1p3 = ws[3];
  u64 a1[4] = {0, 0, 0, 0};  // bit 4*(7*oy+ox)+c, 1 = negative
  int pix = 0;
  #pragma unroll
  for (int oy = 0; oy < 7; ++oy) {
    const u32 r0 = rb[2 * oy], r1 = rb[2 * oy + 1], r2 = rb[2 * oy + 2];
    #pragma unroll
    for (int ox = 0; ox < 7; ++ox) {
      const u32 t9 = ((r0 >> (2 * ox)) & 7) | (((r1 >> (2 * ox)) & 7) << 3)
                   | (((r2 >> (2 * ox)) & 7) << 6);
      u32 nib = 0;
      nib |= (u32)(__popc(t9 ^ w1p0) >= 5) << 0;
      nib |= (u32)(__popc(t9 ^ w1p1) >= 5) << 1;
      nib |= (u32)(__popc(t9 ^ w1p2) >= 5) << 2;
      nib |= (u32)(__popc(t9 ^ w1p3) >= 5) << 3;
      a1[pix >> 4] |= (u64)nib << ((pix & 15) * 4);
      ++pix;
    }
  }

  // ---- Layer 2: 8ch, 7x7 -> 3x3, 36 taps (ternary out) ----
  const u64* w2qp = (const u64*)(ws + 8);
  u64 W2[8];
  #pragma unroll
  for (int d = 0; d < 8; ++d) W2[d] = w2qp[d];
  u64 v2lo = 0, nz2lo = 0; u32 v2hi = 0, nz2hi = 0;  // bit 8*(3*oy+ox)+d
  #pragma unroll
  for (int oy = 0; oy < 3; ++oy) {
    #pragma unroll
    for (int ox = 0; ox < 3; ++ox) {
      u64 T = 0;
      #pragma unroll
      for (int ky = 0; ky < 3; ++ky) {
        const int p = 4 * (7 * (2 * oy + ky) + 2 * ox);
        const int w = p >> 6, o = p & 63;
        u64 v = a1[w] >> o;
        if (o > 52) v |= a1[w + 1] << (64 - o);
        T |= (v & 0xFFFull) << (12 * ky);
      }
      const int pix2 = 3 * oy + ox;
      u32 bv = 0, bz = 0;
      #pragma unroll
      for (int d = 0; d < 8; ++d) {
        const int cnt = __popcll(T ^ W2[d]);  // #neg products of 36
        bv |= (u32)(cnt > 18) << d;           // sum = 36-2cnt < 0
        bz |= (u32)(cnt != 18) << d;          // nonzero
      }
      if (pix2 < 8) { v2lo |= (u64)bv << (8 * pix2); nz2lo |= (u64)bz << (8 * pix2); }
      else          { v2hi = bv; nz2hi = bz; }
    }
  }

  // ---- Layer 3: 16ch, 3x3 -> 1x1, 72 taps, ternary in/out ----
  const u64* w3lo = (const u64*)(ws + 24);
  const u32* w3hi = ws + 56;
  u64 W3L[16]; u32 W3H[16];
  #pragma unroll
  for (int e = 0; e < 16; ++e) { W3L[e] = w3lo[e]; W3H[e] = w3hi[e]; }
  const int nztot = __popcll(nz2lo) + __popc(nz2hi);
  u32 s3v = 0, s3nz = 0;
  #pragma unroll
  for (int e = 0; e < 16; ++e) {
    const int cnt = __popcll(nz2lo & (v2lo ^ W3L[e])) + __popc(nz2hi & (v2hi ^ W3H[e]));
    const int s = nztot - 2 * cnt;
    s3v  |= (u32)(s < 0) << e;
    s3nz |= (u32)(s != 0) << e;
  }

  // ---- FC1: 16 -> 8, ternary ----
  const u32* wf1 = ws + 72;
  u32 WF1[8];
  #pragma unroll
  for (int j = 0; j < 8; ++j) WF1[j] = wf1[j];
  const int n3 = __popc(s3nz);
  u32 hv = 0, hz = 0;
  #pragma unroll
  for (int j = 0; j < 8; ++j) {
    const int c2 = __popc(s3nz & (s3v ^ WF1[j]));
    const int s = n3 - 2 * c2;
    hv |= (u32)(s < 0) << j;
    hz |= (u32)(s != 0) << j;
  }

  // ---- FC2: 8 -> 1 (no hardtanh) ----
  const u32 wf2 = ws[80];
  const int c3 = __popc(hz & (hv ^ wf2));
  const int sfin = __popc(hz) - 2 * c3;
  out[b0 + lane] = (float)sfin;
}

extern "C" void kernel_launch(void* const* d_in, const int* in_sizes, int n_in,
                              void* d_out, int out_size, void* d_ws, size_t ws_size,
                              hipStream_t stream) {
  const float* x    = (const float*)d_in[0];
  const float* w1   = (const float*)d_in[1];
  const float* w2   = (const float*)d_in[2];
  const float* w3   = (const float*)d_in[3];
  const float* wfc1 = (const float*)d_in[4];
  const float* wfc2 = (const float*)d_in[5];
  u32* ws = (u32*)d_ws;
  float* out = (float*)d_out;
  const int B = in_sizes[0] / 225;  // 131072

  prep_weights<<<1, 1024, 0, stream>>>(w1, w2, w3, wfc1, wfc2, ws);
  binnet<<<B / 64, 64, 0, stream>>>(x, ws, out);
}

// Round 2
// 185.630 us; speedup vs baseline: 1.0374x; 1.0238x over previous
//
#include <hip/hip_runtime.h>
#include <stdint.h>

typedef uint32_t u32;
typedef uint64_t u64;

// BinaryNet on MI355X: everything after binarize() is {-1,0,+1}.
// Layer1 (9 taps, odd) -> exact +-1 per output -> 1 bit.
// Layer2 (36 taps, even) -> ternary -> (value bit, nonzero bit).
// All convs/FCs computed as XOR + popcount on packed sign bits.
//
// R7: single-kernel design. The separate prep_weights launch (1 workgroup,
// 1612 atomics, fully serialized before binnet) is folded into binnet as
// ballot-gather weight packing: each lane loads the weight element whose
// TARGET bit position equals its lane index, so one __ballot produces each
// packed word directly (inverse-permuted gather). ~30 L2-hot loads + ~30
// ballots per wave (~0.2 us), placed AFTER the x-staging loop so the proven
// 45-deep load batch and the ~72 weight VGPRs are never simultaneously live.
// Eval is byte-identical to the verified R3/R4 kernel; only the weight source
// changes (ws loads -> ballot registers, with explicit masking so all bits
// above each word's logical width are zero, matching zero-initialized ws).
//
// Launch shape: <<<B/64, 64>>> (R6, passed bit-exact). 2048 blocks = 8
// independent 1-wave blocks/CU = 2 waves/SIMD; __launch_bounds__(64,2)
// grants the full 256-VGPR budget for that occupancy so the compiler does
// not collapse the 45-deep batch chasing a smaller VGPR target (R4 lesson).
//
// Bit-layout reference (target semantics, identical to prior ws layout):
//   w1p[c]  : 9-bit,  bit 3*ky+kx
//   W2[d]   : 36-bit, bit 12*ky+4*kx+c
//   W3L[e]  : 64-bit, bit 8*(3*ky+kx)+d  (taps 0..7)
//   W3H[e]  : 8-bit,  bit d              (tap 8, i.e. ky=kx=2)
//   WF1[j]  : 16-bit, bit e
//   wf2     : 8-bit,  bit j

__global__ __launch_bounds__(64, 2) void binnet(const float* __restrict__ x,
                                                const float* __restrict__ w1,
                                                const float* __restrict__ w2,
                                                const float* __restrict__ w3,
                                                const float* __restrict__ wfc1,
                                                const float* __restrict__ wfc2,
                                                float* __restrict__ out) {
  __shared__ u64 st[228];
  const int lane = threadIdx.x;       // one wave per block
  const int b0 = blockIdx.x * 64;     // this block's 64 samples

  // ---- Stage this wave's 64 samples' 225 sign words (flat float order) ----
  // word t = ballot over lanes of float [b0*225 + 64t + lane].
  // 5 groups of 45: all 45 coalesced loads issue before the ballot/store
  // drain (45 live floats ~ 55 VGPRs).
  const float* xw = x + (size_t)b0 * 225 + lane;
  if (lane < 3) st[225 + lane] = 0;   // zero tail words
  #pragma unroll
  for (int g = 0; g < 5; ++g) {
    float v[45];
    #pragma unroll
    for (int k = 0; k < 45; ++k) v[k] = xw[(g * 45 + k) * 64];
    #pragma unroll
    for (int k = 0; k < 45; ++k) {
      const u64 m = __ballot(v[k] < 0.f);
      if (lane == 0) st[g * 45 + k] = m;
    }
  }

  // ---- Weight packing via inverse-permuted sign ballots ----
  // w1 [4][9]: memory order c*9+k == bit order 9c+k. One ballot.
  const float vw1 = w1[lane < 36 ? lane : 0];
  const u64 m1 = __ballot((lane < 36) && (vw1 < 0.f));
  const u32 w1p0 = (u32)(m1      ) & 0x1FFu;
  const u32 w1p1 = (u32)(m1 >>  9) & 0x1FFu;
  const u32 w1p2 = (u32)(m1 >> 18) & 0x1FFu;
  const u32 w1p3 = (u32)(m1 >> 27) & 0x1FFu;

  // w2 [8][4][3][3]: target bit bp = 4t+c (t=3ky+kx) <- mem d*36 + c*9 + t.
  // Lane bp loads (bp&3)*9 + (bp>>2); lanes >=36 clamped + predicated off.
  const int w2i = (lane < 36) ? ((lane & 3) * 9 + (lane >> 2)) : 0;
  u64 W2[8];
  #pragma unroll
  for (int d = 0; d < 8; ++d) {
    const float v = w2[d * 36 + w2i];
    W2[d] = __ballot((lane < 36) && (v < 0.f));   // bits >=36 are 0
  }

  // w3 [16][8][3][3]: target bit bp = 8t+d <- mem e*72 + d*9 + t.
  // Lo (t=0..7): lane l loads e*72 + (l&7)*9 + (l>>3)  -> bit l = 8t+d.
  // Hi (t=8): two combined ballots, 8 channels' bit-d bytes per ballot.
  const int w3i = (lane & 7) * 9 + (lane >> 3);
  u64 W3L[16];
  u32 W3H[16];
  #pragma unroll
  for (int e = 0; e < 16; ++e) W3L[e] = __ballot(w3[e * 72 + w3i] < 0.f);
  {
    const int hb = (lane & 7) * 9 + 8;
    const u64 h0 = __ballot(w3[((lane >> 3)    ) * 72 + hb] < 0.f);
    const u64 h1 = __ballot(w3[((lane >> 3) + 8) * 72 + hb] < 0.f);
    #pragma unroll
    for (int e = 0; e < 16; ++e)
      W3H[e] = (u32)(((e < 8 ? h0 : h1) >> (8 * (e & 7))) & 0xFFu);
  }

  // wfc1 [8][16]: memory order j*16+e == bit order. Two ballots.
  const u64 f0 = __ballot(wfc1[lane] < 0.f);
  const u64 f1 = __ballot(wfc1[64 + lane] < 0.f);
  u32 WF1[8];
  #pragma unroll
  for (int j = 0; j < 8; ++j)
    WF1[j] = (u32)(((j < 4 ? f0 : f1) >> (16 * (j & 3))) & 0xFFFFu);

  // wfc2 [1][8]
  const float vf2 = wfc2[lane < 8 ? lane : 0];
  const u32 wf2 = (u32)__ballot((lane < 8) && (vf2 < 0.f)) & 0xFFu;

  __syncthreads();  // single-wave barrier: orders LDS ballot-stores -> reads

  // ---- Eval: byte-identical to the verified R3/R4 kernel ----
  const u64* stw = st;
  const int f0i = 225 * lane;
  const int w0 = f0i >> 6;
  const int sh = f0i & 63;
  u64 Wd[5];
  #pragma unroll
  for (int i = 0; i < 5; ++i) Wd[i] = stw[w0 + i];
  u64 Bv[4];
  #pragma unroll
  for (int i = 0; i < 4; ++i)
    Bv[i] = (Wd[i] >> sh) | ((Wd[i + 1] << (63 - sh)) << 1);  // sh==0 -> 0 contribution

  // rows: rb[r] bit k = sign(x[b,0,r,k])
  u32 rb[15];
  #pragma unroll
  for (int r = 0; r < 15; ++r) {
    const int f = 15 * r, w = f >> 6, o = f & 63;
    u64 v = Bv[w] >> o;
    if (o > 49) v |= Bv[w + 1] << (64 - o);
    rb[r] = (u32)v & 0x7FFFu;
  }

  // ---- Layer 1: 4ch, 15x15 -> 7x7, 9 taps (always +-1 out) ----
  u64 a1[4] = {0, 0, 0, 0};  // bit 4*(7*oy+ox)+c, 1 = negative
  int pix = 0;
  #pragma unroll
  for (int oy = 0; oy < 7; ++oy) {
    const u32 r0 = rb[2 * oy], r1 = rb[2 * oy + 1], r2 = rb[2 * oy + 2];
    #pragma unroll
    for (int ox = 0; ox < 7; ++ox) {
      const u32 t9 = ((r0 >> (2 * ox)) & 7) | (((r1 >> (2 * ox)) & 7) << 3)
                   | (((r2 >> (2 * ox)) & 7) << 6);
      u32 nib = 0;
      nib |= (u32)(__popc(t9 ^ w1p0) >= 5) << 0;
      nib |= (u32)(__popc(t9 ^ w1p1) >= 5) << 1;
      nib |= (u32)(__popc(t9 ^ w1p2) >= 5) << 2;
      nib |= (u32)(__popc(t9 ^ w1p3) >= 5) << 3;
      a1[pix >> 4] |= (u64)nib << ((pix & 15) * 4);
      ++pix;
    }
  }

  // ---- Layer 2: 8ch, 7x7 -> 3x3, 36 taps (ternary out) ----
  u64 v2lo = 0, nz2lo = 0; u32 v2hi = 0, nz2hi = 0;  // bit 8*(3*oy+ox)+d
  #pragma unroll
  for (int oy = 0; oy < 3; ++oy) {
    #pragma unroll
    for (int ox = 0; ox < 3; ++ox) {
      u64 T = 0;
      #pragma unroll
      for (int ky = 0; ky < 3; ++ky) {
        const int p = 4 * (7 * (2 * oy + ky) + 2 * ox);
        const int w = p >> 6, o = p & 63;
        u64 v = a1[w] >> o;
        if (o > 52) v |= a1[w + 1] << (64 - o);
        T |= (v & 0xFFFull) << (12 * ky);
      }
      const int pix2 = 3 * oy + ox;
      u32 bv = 0, bz = 0;
      #pragma unroll
      for (int d = 0; d < 8; ++d) {
        const int cnt = __popcll(T ^ W2[d]);  // #neg products of 36
        bv |= (u32)(cnt > 18) << d;           // sum = 36-2cnt < 0
        bz |= (u32)(cnt != 18) << d;          // nonzero
      }
      if (pix2 < 8) { v2lo |= (u64)bv << (8 * pix2); nz2lo |= (u64)bz << (8 * pix2); }
      else          { v2hi = bv; nz2hi = bz; }
    }
  }

  // ---- Layer 3: 16ch, 3x3 -> 1x1, 72 taps, ternary in/out ----
  const int nztot = __popcll(nz2lo) + __popc(nz2hi);
  u32 s3v = 0, s3nz = 0;
  #pragma unroll
  for (int e = 0; e < 16; ++e) {
    const int cnt = __popcll(nz2lo & (v2lo ^ W3L[e])) + __popc(nz2hi & (v2hi ^ W3H[e]));
    const int s = nztot - 2 * cnt;
    s3v  |= (u32)(s < 0) << e;
    s3nz |= (u32)(s != 0) << e;
  }

  // ---- FC1: 16 -> 8, ternary ----
  const int n3 = __popc(s3nz);
  u32 hv = 0, hz = 0;
  #pragma unroll
  for (int j = 0; j < 8; ++j) {
    const int c2 = __popc(s3nz & (s3v ^ WF1[j]));
    const int s = n3 - 2 * c2;
    hv |= (u32)(s < 0) << j;
    hz |= (u32)(s != 0) << j;
  }

  // ---- FC2: 8 -> 1 (no hardtanh) ----
  const int c3 = __popc(hz & (hv ^ wf2));
  const int sfin = __popc(hz) - 2 * c3;
  out[b0 + lane] = (float)sfin;
}

extern "C" void kernel_launch(void* const* d_in, const int* in_sizes, int n_in,
                              void* d_out, int out_size, void* d_ws, size_t ws_size,
                              hipStream_t stream) {
  const float* x    = (const float*)d_in[0];
  const float* w1   = (const float*)d_in[1];
  const float* w2   = (const float*)d_in[2];
  const float* w3   = (const float*)d_in[3];
  const float* wfc1 = (const float*)d_in[4];
  const float* wfc2 = (const float*)d_in[5];
  float* out = (float*)d_out;
  const int B = in_sizes[0] / 225;  // 131072

  (void)d_ws; (void)ws_size; (void)n_in; (void)out_size;
  binnet<<<B / 64, 64, 0, stream>>>(x, w1, w2, w3, wfc1, wfc2, out);
}